// Round 5
// baseline (678.937 us; speedup 1.0000x reference)
//
#include <hip/hip_runtime.h>

// SparseWeights: y = x @ (W_dense + scatter(sparse))^T + bias
// Round 5 (= round 4 resubmit after infra flake): 256x256 tile, BK=32.
// B (weights) staged through a 4-deep LDS ring (64 KiB, zero-conflict
// swizzle); A (activations) fragments loaded DIRECTLY global->register,
// double-buffered, kept in flight across the MFMA cluster with counted
// vmcnt. One barrier per K-tile. Rationale: r2/r3 measured the LDS pipe
// (96 ds_read_b128 + 32KB writes/iter/CU ~ 1530cy) serializing with MFMA
// (1241cy); moving A out of LDS cuts LDS pipe to ~570cy << MFMA.

typedef __attribute__((ext_vector_type(8))) __bf16 bf16x8;
typedef __attribute__((ext_vector_type(4))) float f32x4;
typedef __attribute__((ext_vector_type(8))) unsigned short u16x8;

#define BARRIER()   asm volatile("s_barrier" ::: "memory")
#define WAITLGKM(n) asm volatile("s_waitcnt lgkmcnt(" #n ")" ::: "memory")
#define WAITVM(n)   asm volatile("s_waitcnt vmcnt(" #n ")" ::: "memory")
#define SCHED0()    __builtin_amdgcn_sched_barrier(0)

__device__ __forceinline__ unsigned short f2bf(float f) {
  unsigned int u = __builtin_bit_cast(unsigned int, f);
  u += 0x7FFFu + ((u >> 16) & 1u);   // round-to-nearest-even
  return (unsigned short)(u >> 16);
}

// ---- prepass 1/3: f32 -> bf16 bulk convert (vectorized x8) ----
__global__ __launch_bounds__(256) void cvt_f32_bf16(
    const float* __restrict__ s, unsigned short* __restrict__ d, long n8) {
  long i = (long)blockIdx.x * blockDim.x + threadIdx.x;
  const long stride = (long)gridDim.x * blockDim.x;
  for (; i < n8; i += stride) {
    const float4* sp = (const float4*)(s + i * 8);
    float4 a = sp[0];
    float4 b = sp[1];
    u16x8 o;
    o[0] = f2bf(a.x); o[1] = f2bf(a.y); o[2] = f2bf(a.z); o[3] = f2bf(a.w);
    o[4] = f2bf(b.x); o[5] = f2bf(b.y); o[6] = f2bf(b.z); o[7] = f2bf(b.w);
    *(u16x8*)(d + i * 8) = o;
  }
}

// ---- prepass 2/3: scatter sparse values into bf16 W ----
__global__ __launch_bounds__(256) void sparse_scatter(
    const float* __restrict__ dense, const float* __restrict__ vals,
    const int* __restrict__ rows, const int* __restrict__ cols,
    unsigned short* __restrict__ Wb, int nnz, int K) {
  int i = blockIdx.x * blockDim.x + threadIdx.x;
  if (i < nnz) {
    size_t off = (size_t)rows[i] * (size_t)K + (size_t)cols[i];
    Wb[off] = f2bf(dense[off] + vals[i]);
  }
}

// =====================================================================
// 256x256 GEMM, 512 threads = 8 waves (2Mx4N), wave tile 128x64 =
// acc[8][4] 16x16x32 frags. BK=32.
//  - B ring: 4 x 16KB LDS (rows 0..255 x 64B), staged via global_load_lds
//    (linear dest, source quad pre-swizzled q^=((r>>1)&3); swizzled
//    ds_read -> 0 bank conflicts, verified r2).
//  - A frags: global->reg, double-buffered (aA/aB), loaded one K-tile
//    ahead, awaited by counted vmcnt.
// Per iter t: stage B(t+3) [2 vm]; load A(t+1) [8 vm]; WAITVM(10)
// (drains prior iter's {stage B(t+2), A(t)}); ds_read b(t) [4];
// lgkm(0); 32 MFMA (setprio); BARRIER.
// Hazard ledger (re-audited r5): ring t published = staged@t-3,
// vm-drained @t-2's WAITVM, barrier end of t-2 < b-reads@t. Overwrite:
// stage@t hits ring holding tile t-1, whose readers drained lgkm@t-1
// before barrier end of t-1 < stage issue@t. CUR A(t) loaded@t-1 is
// drained by t's WAITVM. Tail t=NT-3: 18 outstanding, WAITVM(8) drains
// {stage(NT-1), A(NT-3)=CUR}; t=NT-2: WAITVM(8) drains A(NT-2)=CUR;
// t=NT-1: WAITVM(0) drains A(NT-1)=CUR.
// =====================================================================
__global__ __launch_bounds__(512, 2) void gemm256(
    const unsigned short* __restrict__ A,   // [Tm][K] bf16
    const unsigned short* __restrict__ B,   // [Mn][K] bf16
    const float* __restrict__ bias,
    float* __restrict__ C,
    int Tm, int Mn, int K) {
  extern __shared__ __align__(16) char smem[];   // 4 rings * 16384 B (B only)

  const int tid  = threadIdx.x;
  const int lane = tid & 63;
  const int wid  = tid >> 6;
  const int wm = (wid >> 2) * 128;
  const int wn = (wid & 3) * 64;

  // T1: XCD-aware bijective swizzle (nwg = 512, % 8 == 0)
  const int nwg = gridDim.x;
  int bid = blockIdx.x;
  if ((nwg & 7) == 0) bid = (bid & 7) * (nwg >> 3) + (bid >> 3);
  const int ntn = Mn >> 8;
  const int bm0 = (bid / ntn) << 8;
  const int bn0 = (bid % ntn) << 8;

  const int NT = K >> 5;             // K-tiles of 32

  // ---- B staging: thread t -> 16B at LDS byte t*16 (linear dest);
  // source quad pre-swizzled: LDS quad q of row r holds global quad
  // q ^ ((r>>1)&3).
  const int srow  = tid >> 2;                        // 0..127 (+128 upper)
  const int squad = (tid & 3) ^ ((tid >> 3) & 3);
  const unsigned short* Bsrc = B + (size_t)(bn0 + srow) * K + squad * 8;
  const size_t rstep = (size_t)128 * K;
  const int ldst = tid * 16;

#define STAGE(RING_OFF, KOFF) do {                                               \
    __builtin_amdgcn_global_load_lds(                                            \
        (const __attribute__((address_space(1))) void*)(Bsrc + (KOFF)),          \
        (__attribute__((address_space(3))) void*)(smem + (RING_OFF) + ldst),     \
        16, 0, 0);                                                               \
    __builtin_amdgcn_global_load_lds(                                            \
        (const __attribute__((address_space(1))) void*)(Bsrc + rstep + (KOFF)),  \
        (__attribute__((address_space(3))) void*)(smem + (RING_OFF) + 8192 + ldst), \
        16, 0, 0);                                                               \
  } while (0)

  // ---- B read offsets (swizzled): row = wn + n*16 + fr, byte =
  // row*64 + ((cq ^ ((fr>>1)&3))<<4).
  const int fr = lane & 15, cq = lane >> 4;
  const int boff = (wn + fr) * 64 + ((cq ^ ((fr >> 1) & 3)) << 4);

  // ---- A fragment per-lane global base: row = bm0 + wm + m*16 + fr,
  // k-chunk = t*32 + cq*8 (16B-aligned bf16x8).
  const unsigned short* Afrag = A + (size_t)(bm0 + wm + fr) * K + cq * 8;
  const size_t mstride = (size_t)16 * K;

  f32x4 acc[8][4] = {};
  bf16x8 aA[8], aB[8], b[4];

  // ---- prologue: stage B rings 0,1,2; load A(0) ----
  STAGE(0, 0);
  STAGE(16384, 32);
  STAGE(32768, 64);
#pragma unroll
  for (int m = 0; m < 8; ++m)
    aA[m] = *(const bf16x8*)(Afrag + m * mstride);
  WAITVM(8);    // drain the 6 stage loads (A(0)'s 8 stay in flight)
  BARRIER();    // ring 0..2 published

#define BODY(T, CUR, NXT) do {                                                   \
    const int t_ = (T);                                                          \
    if (t_ + 3 < NT) STAGE(((t_ + 3) & 3) * 16384, (t_ + 3) * 32);               \
    if (t_ + 1 < NT) {                                                           \
      const size_t ko_ = (size_t)(t_ + 1) * 32;                                  \
      _Pragma("unroll")                                                          \
      for (int m = 0; m < 8; ++m)                                                \
        NXT[m] = *(const bf16x8*)(Afrag + m * mstride + ko_);                    \
    }                                                                            \
    if (t_ + 3 < NT)      { WAITVM(10); }                                        \
    else if (t_ + 1 < NT) { WAITVM(8); }                                         \
    else                  { WAITVM(0); }                                         \
    {                                                                            \
      const char* Br_ = smem + (t_ & 3) * 16384;                                 \
      _Pragma("unroll")                                                          \
      for (int n = 0; n < 4; ++n)                                                \
        b[n] = *(const bf16x8*)(Br_ + boff + n * 1024);                          \
    }                                                                            \
    WAITLGKM(0);                                                                 \
    SCHED0();                                                                    \
    __builtin_amdgcn_s_setprio(1);                                               \
    _Pragma("unroll")                                                            \
    for (int m = 0; m < 8; ++m)                                                  \
      _Pragma("unroll")                                                          \
      for (int n = 0; n < 4; ++n)                                                \
        acc[m][n] = __builtin_amdgcn_mfma_f32_16x16x32_bf16(CUR[m], b[n],        \
                                                            acc[m][n], 0, 0, 0);\
    __builtin_amdgcn_s_setprio(0);                                               \
    BARRIER();                                                                   \
  } while (0)

  for (int t = 0; t < NT; t += 2) {
    BODY(t,     aA, aB);
    BODY(t + 1, aB, aA);
  }
#undef BODY
#undef STAGE

  // ---- epilogue: C/D layout col = lane&15, row = (lane>>4)*4 + q ----
  const int c4 = cq * 4;
#pragma unroll
  for (int n = 0; n < 4; ++n) {
    const int col = bn0 + wn + n * 16 + fr;
    const float bv = bias[col];
#pragma unroll
    for (int m = 0; m < 8; ++m) {
      const size_t rowb = (size_t)(bm0 + wm + m * 16 + c4);
#pragma unroll
      for (int q = 0; q < 4; ++q)
        C[(rowb + q) * (size_t)Mn + col] = acc[m][n][q] + bv;
    }
  }
}

extern "C" void kernel_launch(void* const* d_in, const int* in_sizes, int n_in,
                              void* d_out, int out_size, void* d_ws, size_t ws_size,
                              hipStream_t stream) {
  const float* x     = (const float*)d_in[0];
  const float* dw    = (const float*)d_in[1];
  const float* bias  = (const float*)d_in[2];
  const float* sv    = (const float*)d_in[3];
  const int*   rows  = (const int*)d_in[4];
  const int*   cols  = (const int*)d_in[5];
  float* out = (float*)d_out;

  const int  Mn = in_sizes[2];                       // 4096
  const long wElems = (long)in_sizes[1];             // M*K
  const int  K  = (int)(wElems / Mn);                // 4096
  const long xElems = (long)in_sizes[0];             // T*K
  const int  Tm = (int)(xElems / K);                 // 8192
  const int  nnz = in_sizes[3];

  unsigned short* Wb = (unsigned short*)d_ws;        // [M*K] bf16
  unsigned short* Xb = Wb + wElems;                  // [T*K] bf16

  cvt_f32_bf16<<<2048, 256, 0, stream>>>(dw, Wb, wElems / 8);
  sparse_scatter<<<(nnz + 255) / 256, 256, 0, stream>>>(dw, sv, rows, cols, Wb, nnz, K);
  cvt_f32_bf16<<<2048, 256, 0, stream>>>(x, Xb, xElems / 8);

  dim3 grid((Tm >> 8) * (Mn >> 8));                  // 32*16 = 512
  gemm256<<<grid, 512, 65536, stream>>>(Xb, Wb, bias, out, Tm, Mn, K);
}

// Round 6
// 313.609 us; speedup vs baseline: 2.1649x; 2.1649x over previous
//
#include <hip/hip_runtime.h>

// SparseWeights: y = x @ (W_dense + scatter(sparse))^T + bias
// Round 6: 8-phase 256x256 GEMM (catalog T1+T2+T3+T4+T5). BK=64, double-
// buffered LDS (2 x (A 32K + B 32K) = 128 KiB). Per K-tile: 4 phases of
// {ds_read burst + half-tile stage -> barrier -> 16-MFMA quadrant -> barrier},
// single vmcnt(0) per tile at P4 (newest stage ~2 phases old). No manual
// lgkm drains: compiler emits fine-grained counted lgkm waits per fragment.
// r5 lesson: A direct-from-global scatters 16 segments/instr -> 2.3x slower;
// both operands stay in LDS via global_load_lds (contiguous 1KB/wave-instr).

typedef __attribute__((ext_vector_type(8))) __bf16 bf16x8;
typedef __attribute__((ext_vector_type(4))) float f32x4;
typedef __attribute__((ext_vector_type(8))) unsigned short u16x8;

#define BARRIER()   asm volatile("s_barrier" ::: "memory")
#define WAITVM0()   asm volatile("s_waitcnt vmcnt(0)" ::: "memory")

__device__ __forceinline__ unsigned short f2bf(float f) {
  unsigned int u = __builtin_bit_cast(unsigned int, f);
  u += 0x7FFFu + ((u >> 16) & 1u);   // round-to-nearest-even
  return (unsigned short)(u >> 16);
}

// ---- prepass 1/3: f32 -> bf16 bulk convert (vectorized x8) ----
__global__ __launch_bounds__(256) void cvt_f32_bf16(
    const float* __restrict__ s, unsigned short* __restrict__ d, long n8) {
  long i = (long)blockIdx.x * blockDim.x + threadIdx.x;
  const long stride = (long)gridDim.x * blockDim.x;
  for (; i < n8; i += stride) {
    const float4* sp = (const float4*)(s + i * 8);
    float4 a = sp[0];
    float4 b = sp[1];
    u16x8 o;
    o[0] = f2bf(a.x); o[1] = f2bf(a.y); o[2] = f2bf(a.z); o[3] = f2bf(a.w);
    o[4] = f2bf(b.x); o[5] = f2bf(b.y); o[6] = f2bf(b.z); o[7] = f2bf(b.w);
    *(u16x8*)(d + i * 8) = o;
  }
}

// ---- prepass 2/3: scatter sparse values into bf16 W ----
__global__ __launch_bounds__(256) void sparse_scatter(
    const float* __restrict__ dense, const float* __restrict__ vals,
    const int* __restrict__ rows, const int* __restrict__ cols,
    unsigned short* __restrict__ Wb, int nnz, int K) {
  int i = blockIdx.x * blockDim.x + threadIdx.x;
  if (i < nnz) {
    size_t off = (size_t)rows[i] * (size_t)K + (size_t)cols[i];
    Wb[off] = f2bf(dense[off] + vals[i]);
  }
}

// =====================================================================
// 256x256 GEMM, 512 threads = 8 waves (2Mx4N), wave tile 128x64 =
// acc[8][4] of 16x16x32 frags, BK=64 (2 k-sub-steps kk=0,1 per frag col).
// LDS per buffer: A[256 rows][64 k] (32 KB) @ 0, B @ 32768. Rows = 128 B
// = 8 16B-quads; LDS quad q of row r holds global quad q ^ (r&7)
// (pre-swizzled source, swizzled ds_read; 2 lanes/bank-group = free).
// Phases per K-tile t (buffer cur = t&1, staging tile t+1 into cur^1):
//  P1: read A[m0-3,kk01](8) + B[n0-1,kk01](4); stage A-h0,A-h1(t+1);
//      BARRIER; prio1; 16 MFMA (q00); prio0; BARRIER.
//  P2: read B[n2-3](4); stage B-h0,B-h1(t+1); BARRIER; q01; BARRIER.
//  P3: read A[m4-7](8) (reuse regs); BARRIER; q10; BARRIER.
//  P4: q11; WAITVM0 (t+1's 8 stages, newest ~2 phases old); BARRIER.
// Publish: stages(t+1) drained at t's P4 vmcnt(0) before barrier ->
// t+1's P1 reads safe. WAW: stages(t+1) target cur^1, last read in
// t-1's phases (reads complete before their phase's MFMA auto-wait,
// before t-1's trailing barriers < t's P1 stage issue).
// =====================================================================
__global__ __launch_bounds__(512, 2) void gemm256p(
    const unsigned short* __restrict__ A,   // [Tm][K] bf16
    const unsigned short* __restrict__ B,   // [Mn][K] bf16
    const float* __restrict__ bias,
    float* __restrict__ C,
    int Tm, int Mn, int K) {
  extern __shared__ __align__(16) char smem[];   // 2 x 65536

  const int tid  = threadIdx.x;
  const int lane = tid & 63;
  const int wid  = tid >> 6;
  const int wm = (wid >> 2) * 128;
  const int wn = (wid & 3) * 64;

  // T1: XCD-aware bijective swizzle (nwg = 512, % 8 == 0)
  const int nwg = gridDim.x;
  int bid = blockIdx.x;
  if ((nwg & 7) == 0) bid = (bid & 7) * (nwg >> 3) + (bid >> 3);
  const int ntn = Mn >> 8;
  const int bm0 = (bid / ntn) << 8;
  const int bn0 = (bid % ntn) << 8;

  const int NT = K >> 6;             // K-tiles of 64

  // ---- staging: thread t writes 16B to LDS byte (half)+(L*8192)+t*16
  // -> row L*64 + (t>>3), quad t&7. Source holds global quad
  // (t&7)^((t>>3)&7) of global row (half*128 + L*64 + (t>>3)).
  const int sr  = tid >> 3;                          // 0..63
  const int gq8 = ((tid & 7) ^ (sr & 7)) * 8;        // pre-swizzled elem off
  const unsigned short* Asrc = A + (size_t)(bm0 + sr) * K + gq8;
  const unsigned short* Bsrc = B + (size_t)(bn0 + sr) * K + gq8;
  const size_t r64 = (size_t)64 * K;
  const int ldst = tid * 16;

#define STAGEH(SRC, H, LDSB, KOFF) do {                                          \
    __builtin_amdgcn_global_load_lds(                                            \
      (const __attribute__((address_space(1))) void*)((SRC) + (size_t)(H)*2*r64 + (KOFF)), \
      (__attribute__((address_space(3))) void*)(smem + (LDSB) + ldst), 16, 0, 0);\
    __builtin_amdgcn_global_load_lds(                                            \
      (const __attribute__((address_space(1))) void*)((SRC) + (size_t)(H)*2*r64 + r64 + (KOFF)), \
      (__attribute__((address_space(3))) void*)(smem + (LDSB) + 8192 + ldst), 16, 0, 0); \
  } while (0)

  // ---- read offsets: frag (row R, kk, cq) -> byte R*128 + ((kk*4+cq)^(R&7))*16
  const int fr = lane & 15, cq = lane >> 4;
  const int f7 = fr & 7;
  const int q0 = ((cq ^ f7) << 4);          // kk = 0
  const int q1 = (((4 + cq) ^ f7) << 4);    // kk = 1
  const int arow = (wm + fr) * 128;
  const int brow = (wn + fr) * 128;

  f32x4 acc[8][4] = {};
  bf16x8 aq0[4], aq1[4], bA0[2], bA1[2], bB0[2], bB1[2];

  // ---- prologue: stage tile 0 into buf 0 ----
  STAGEH(Asrc, 0, 0, 0);
  STAGEH(Asrc, 1, 16384, 0);
  STAGEH(Bsrc, 0, 32768, 0);
  STAGEH(Bsrc, 1, 49152, 0);
  WAITVM0();
  BARRIER();

#pragma unroll 2
  for (int t = 0; t < NT; ++t) {
    const char* Ab = smem + (t & 1) * 65536;
    const char* Bb = Ab + 32768;
    const int nbase = ((t & 1) ^ 1) * 65536;
    const int kn = (t + 1) * 64;
    const bool st = (t + 1 < NT);

    // ---- P1: A quad m0-3 + B n0-1; stage A halves of t+1 ----
#pragma unroll
    for (int m = 0; m < 4; ++m) {
      aq0[m] = *(const bf16x8*)(Ab + arow + m * 2048 + q0);
      aq1[m] = *(const bf16x8*)(Ab + arow + m * 2048 + q1);
    }
#pragma unroll
    for (int n = 0; n < 2; ++n) {
      bA0[n] = *(const bf16x8*)(Bb + brow + n * 2048 + q0);
      bA1[n] = *(const bf16x8*)(Bb + brow + n * 2048 + q1);
    }
    if (st) { STAGEH(Asrc, 0, nbase, kn); STAGEH(Asrc, 1, nbase + 16384, kn); }
    BARRIER();
    __builtin_amdgcn_s_setprio(1);
#pragma unroll
    for (int m = 0; m < 4; ++m)
#pragma unroll
      for (int n = 0; n < 2; ++n) {
        acc[m][n] = __builtin_amdgcn_mfma_f32_16x16x32_bf16(aq0[m], bA0[n], acc[m][n], 0, 0, 0);
        acc[m][n] = __builtin_amdgcn_mfma_f32_16x16x32_bf16(aq1[m], bA1[n], acc[m][n], 0, 0, 0);
      }
    __builtin_amdgcn_s_setprio(0);
    BARRIER();

    // ---- P2: B n2-3; stage B halves of t+1 ----
#pragma unroll
    for (int n = 0; n < 2; ++n) {
      bB0[n] = *(const bf16x8*)(Bb + brow + (n + 2) * 2048 + q0);
      bB1[n] = *(const bf16x8*)(Bb + brow + (n + 2) * 2048 + q1);
    }
    if (st) { STAGEH(Bsrc, 0, nbase + 32768, kn); STAGEH(Bsrc, 1, nbase + 49152, kn); }
    BARRIER();
    __builtin_amdgcn_s_setprio(1);
#pragma unroll
    for (int m = 0; m < 4; ++m)
#pragma unroll
      for (int n = 0; n < 2; ++n) {
        acc[m][n + 2] = __builtin_amdgcn_mfma_f32_16x16x32_bf16(aq0[m], bB0[n], acc[m][n + 2], 0, 0, 0);
        acc[m][n + 2] = __builtin_amdgcn_mfma_f32_16x16x32_bf16(aq1[m], bB1[n], acc[m][n + 2], 0, 0, 0);
      }
    __builtin_amdgcn_s_setprio(0);
    BARRIER();

    // ---- P3: A quad m4-7 (reuse regs) ----
#pragma unroll
    for (int m = 0; m < 4; ++m) {
      aq0[m] = *(const bf16x8*)(Ab + arow + (m + 4) * 2048 + q0);
      aq1[m] = *(const bf16x8*)(Ab + arow + (m + 4) * 2048 + q1);
    }
    BARRIER();
    __builtin_amdgcn_s_setprio(1);
#pragma unroll
    for (int m = 0; m < 4; ++m)
#pragma unroll
      for (int n = 0; n < 2; ++n) {
        acc[m + 4][n] = __builtin_amdgcn_mfma_f32_16x16x32_bf16(aq0[m], bA0[n], acc[m + 4][n], 0, 0, 0);
        acc[m + 4][n] = __builtin_amdgcn_mfma_f32_16x16x32_bf16(aq1[m], bA1[n], acc[m + 4][n], 0, 0, 0);
      }
    __builtin_amdgcn_s_setprio(0);
    BARRIER();

    // ---- P4: q11; drain t+1 stages; publish ----
    __builtin_amdgcn_s_setprio(1);
#pragma unroll
    for (int m = 0; m < 4; ++m)
#pragma unroll
      for (int n = 0; n < 2; ++n) {
        acc[m + 4][n + 2] = __builtin_amdgcn_mfma_f32_16x16x32_bf16(aq0[m], bB0[n], acc[m + 4][n + 2], 0, 0, 0);
        acc[m + 4][n + 2] = __builtin_amdgcn_mfma_f32_16x16x32_bf16(aq1[m], bB1[n], acc[m + 4][n + 2], 0, 0, 0);
      }
    __builtin_amdgcn_s_setprio(0);
    WAITVM0();     // newest stage issued in P2 (~2 phases ago)
    BARRIER();
  }
#undef STAGEH

  // ---- epilogue: C/D layout col = lane&15, row = (lane>>4)*4 + q ----
  const int c4 = cq * 4;
#pragma unroll
  for (int n = 0; n < 4; ++n) {
    const int col = bn0 + wn + n * 16 + fr;
    const float bv = bias[col];
#pragma unroll
    for (int m = 0; m < 8; ++m) {
      const size_t rowb = (size_t)(bm0 + wm + m * 16 + c4);
#pragma unroll
      for (int q = 0; q < 4; ++q)
        C[(rowb + q) * (size_t)Mn + col] = acc[m][n][q] + bv;
    }
  }
}

extern "C" void kernel_launch(void* const* d_in, const int* in_sizes, int n_in,
                              void* d_out, int out_size, void* d_ws, size_t ws_size,
                              hipStream_t stream) {
  const float* x     = (const float*)d_in[0];
  const float* dw    = (const float*)d_in[1];
  const float* bias  = (const float*)d_in[2];
  const float* sv    = (const float*)d_in[3];
  const int*   rows  = (const int*)d_in[4];
  const int*   cols  = (const int*)d_in[5];
  float* out = (float*)d_out;

  const int  Mn = in_sizes[2];                       // 4096
  const long wElems = (long)in_sizes[1];             // M*K
  const int  K  = (int)(wElems / Mn);                // 4096
  const long xElems = (long)in_sizes[0];             // T*K
  const int  Tm = (int)(xElems / K);                 // 8192
  const int  nnz = in_sizes[3];

  unsigned short* Wb = (unsigned short*)d_ws;        // [M*K] bf16
  unsigned short* Xb = Wb + wElems;                  // [T*K] bf16

  cvt_f32_bf16<<<2048, 256, 0, stream>>>(dw, Wb, wElems / 8);
  sparse_scatter<<<(nnz + 255) / 256, 256, 0, stream>>>(dw, sv, rows, cols, Wb, nnz, K);
  cvt_f32_bf16<<<2048, 256, 0, stream>>>(x, Xb, xElems / 8);

  dim3 grid((Tm >> 8) * (Mn >> 8));                  // 32*16 = 512
  gemm256p<<<grid, 512, 131072, stream>>>(Xb, Wb, bias, out, Tm, Mn, K);
}

// Round 7
// 302.530 us; speedup vs baseline: 2.2442x; 1.0366x over previous
//
#include <hip/hip_runtime.h>

// SparseWeights: y = x @ (W_dense + scatter(sparse))^T + bias
// Round 7: barrier-free tile interior. r2/r3/r6 all converged at ~1000 TF
// because block-wide barriers around every phase force all 8 waves to read
// LDS together then MFMA together (pipes serialize). With a full double
// buffer the interior barriers are not needed for correctness: only the
// tile boundary (buffer swap + stage publish) syncs. Per tile: stage(t+1)
// at start (8 gloads, ~3.5 phases of age), 4 unfenced phases of
// {ds_reads -> lgkm(0) -> sched_barrier -> setprio+16 MFMA}, then one
// vmcnt(0) (old loads => ~free) + one s_barrier. Waves stagger naturally,
// overlapping LDS reads with other waves' MFMA (m114 mechanism in-block).

typedef __attribute__((ext_vector_type(8))) __bf16 bf16x8;
typedef __attribute__((ext_vector_type(4))) float f32x4;
typedef __attribute__((ext_vector_type(8))) unsigned short u16x8;

#define BARRIER()   asm volatile("s_barrier" ::: "memory")
#define WAITLGKM0() asm volatile("s_waitcnt lgkmcnt(0)" ::: "memory")
#define WAITVM0()   asm volatile("s_waitcnt vmcnt(0)" ::: "memory")
#define SCHED0()    __builtin_amdgcn_sched_barrier(0)

__device__ __forceinline__ unsigned short f2bf(float f) {
  unsigned int u = __builtin_bit_cast(unsigned int, f);
  u += 0x7FFFu + ((u >> 16) & 1u);   // round-to-nearest-even
  return (unsigned short)(u >> 16);
}

// ---- prepass 1/3: f32 -> bf16 bulk convert (vectorized x8) ----
__global__ __launch_bounds__(256) void cvt_f32_bf16(
    const float* __restrict__ s, unsigned short* __restrict__ d, long n8) {
  long i = (long)blockIdx.x * blockDim.x + threadIdx.x;
  const long stride = (long)gridDim.x * blockDim.x;
  for (; i < n8; i += stride) {
    const float4* sp = (const float4*)(s + i * 8);
    float4 a = sp[0];
    float4 b = sp[1];
    u16x8 o;
    o[0] = f2bf(a.x); o[1] = f2bf(a.y); o[2] = f2bf(a.z); o[3] = f2bf(a.w);
    o[4] = f2bf(b.x); o[5] = f2bf(b.y); o[6] = f2bf(b.z); o[7] = f2bf(b.w);
    *(u16x8*)(d + i * 8) = o;
  }
}

// ---- prepass 2/3: scatter sparse values into bf16 W ----
__global__ __launch_bounds__(256) void sparse_scatter(
    const float* __restrict__ dense, const float* __restrict__ vals,
    const int* __restrict__ rows, const int* __restrict__ cols,
    unsigned short* __restrict__ Wb, int nnz, int K) {
  int i = blockIdx.x * blockDim.x + threadIdx.x;
  if (i < nnz) {
    size_t off = (size_t)rows[i] * (size_t)K + (size_t)cols[i];
    Wb[off] = f2bf(dense[off] + vals[i]);
  }
}

// =====================================================================
// 256x256 GEMM, 512 threads = 8 waves (2Mx4N), wave tile 128x64 =
// acc[8][4] of 16x16x32 frags, BK=64 (kk=0,1). LDS: 2 x (A 32K + B 32K)
// = 128 KiB dbuf. Rows = 128 B = 8 quads; LDS quad q of row r holds
// global quad q^(r&7) (pre-swizzled source, swizzled read; pass-level
// conflict-free, 0 conflicts measured r6).
// Tile t (buf = t&1): stage(t+1 -> buf^1) [8 gloads]; P1 reads(12)+q00;
// P2 reads(4)+q01; P3 reads(8)+q10; P4 q11 — NO barriers between phases,
// per-phase own-wave lgkm(0)+sched_barrier only; then WAITVM0 (stages
// ~3.5 phases old) + BARRIER.
// Publish ledger: stages(t) issued at t-1 start, drained by each wave's
// WAITVM0 at t-1 end, barrier -> visible for t's reads. WAW: stage(t+1)
// writes buf^1, whose last readers (tile t-1) finished before the
// barrier ending t-1 < stage issue at t start.
// =====================================================================
__global__ __launch_bounds__(512, 2) void gemm256f(
    const unsigned short* __restrict__ A,   // [Tm][K] bf16
    const unsigned short* __restrict__ B,   // [Mn][K] bf16
    const float* __restrict__ bias,
    float* __restrict__ C,
    int Tm, int Mn, int K) {
  extern __shared__ __align__(16) char smem[];   // 2 x 65536

  const int tid  = threadIdx.x;
  const int lane = tid & 63;
  const int wid  = tid >> 6;
  const int wm = (wid >> 2) * 128;
  const int wn = (wid & 3) * 64;

  // T1: XCD-aware bijective swizzle (nwg = 512, % 8 == 0)
  const int nwg = gridDim.x;
  int bid = blockIdx.x;
  if ((nwg & 7) == 0) bid = (bid & 7) * (nwg >> 3) + (bid >> 3);
  const int ntn = Mn >> 8;
  const int bm0 = (bid / ntn) << 8;
  const int bn0 = (bid % ntn) << 8;

  const int NT = K >> 6;             // K-tiles of 64

  // ---- staging (identical mapping to r6, correctness-verified) ----
  const int sr  = tid >> 3;                          // 0..63
  const int gq8 = ((tid & 7) ^ (sr & 7)) * 8;        // pre-swizzled elem off
  const unsigned short* Asrc = A + (size_t)(bm0 + sr) * K + gq8;
  const unsigned short* Bsrc = B + (size_t)(bn0 + sr) * K + gq8;
  const size_t r64 = (size_t)64 * K;
  const int ldst = tid * 16;

#define STAGEH(SRC, H, LDSB, KOFF) do {                                          \
    __builtin_amdgcn_global_load_lds(                                            \
      (const __attribute__((address_space(1))) void*)((SRC) + (size_t)(H)*2*r64 + (KOFF)), \
      (__attribute__((address_space(3))) void*)(smem + (LDSB) + ldst), 16, 0, 0);\
    __builtin_amdgcn_global_load_lds(                                            \
      (const __attribute__((address_space(1))) void*)((SRC) + (size_t)(H)*2*r64 + r64 + (KOFF)), \
      (__attribute__((address_space(3))) void*)(smem + (LDSB) + 8192 + ldst), 16, 0, 0); \
  } while (0)

  // ---- read offsets: frag (row R, kk, cq) -> byte R*128 + ((kk*4+cq)^(R&7))*16
  const int fr = lane & 15, cq = lane >> 4;
  const int f7 = fr & 7;
  const int q0 = ((cq ^ f7) << 4);          // kk = 0
  const int q1 = (((4 + cq) ^ f7) << 4);    // kk = 1
  const int arow = (wm + fr) * 128;
  const int brow = (wn + fr) * 128;

  f32x4 acc[8][4] = {};
  bf16x8 aq0[4], aq1[4], bA0[2], bA1[2], bB0[2], bB1[2];

  // ---- prologue: stage tile 0 into buf 0 ----
  STAGEH(Asrc, 0, 0, 0);
  STAGEH(Asrc, 1, 16384, 0);
  STAGEH(Bsrc, 0, 32768, 0);
  STAGEH(Bsrc, 1, 49152, 0);
  WAITVM0();
  BARRIER();

#pragma unroll 2
  for (int t = 0; t < NT; ++t) {
    const char* Ab = smem + (t & 1) * 65536;
    const char* Bb = Ab + 32768;
    const int nbase = ((t & 1) ^ 1) * 65536;
    const int kn = (t + 1) * 64;

    // ---- stage ALL of tile t+1 at tile start (max latency headroom) ----
    if (t + 1 < NT) {
      STAGEH(Asrc, 0, nbase, kn);
      STAGEH(Asrc, 1, nbase + 16384, kn);
      STAGEH(Bsrc, 0, nbase + 32768, kn);
      STAGEH(Bsrc, 1, nbase + 49152, kn);
    }

    // ---- P1: A m0-3 (8) + B n0-1 (4); q00 ----
#pragma unroll
    for (int m = 0; m < 4; ++m) {
      aq0[m] = *(const bf16x8*)(Ab + arow + m * 2048 + q0);
      aq1[m] = *(const bf16x8*)(Ab + arow + m * 2048 + q1);
    }
#pragma unroll
    for (int n = 0; n < 2; ++n) {
      bA0[n] = *(const bf16x8*)(Bb + brow + n * 2048 + q0);
      bA1[n] = *(const bf16x8*)(Bb + brow + n * 2048 + q1);
    }
    WAITLGKM0();
    SCHED0();
    __builtin_amdgcn_s_setprio(1);
#pragma unroll
    for (int m = 0; m < 4; ++m)
#pragma unroll
      for (int n = 0; n < 2; ++n) {
        acc[m][n] = __builtin_amdgcn_mfma_f32_16x16x32_bf16(aq0[m], bA0[n], acc[m][n], 0, 0, 0);
        acc[m][n] = __builtin_amdgcn_mfma_f32_16x16x32_bf16(aq1[m], bA1[n], acc[m][n], 0, 0, 0);
      }
    __builtin_amdgcn_s_setprio(0);
    SCHED0();

    // ---- P2: B n2-3 (4); q01 ----
#pragma unroll
    for (int n = 0; n < 2; ++n) {
      bB0[n] = *(const bf16x8*)(Bb + brow + (n + 2) * 2048 + q0);
      bB1[n] = *(const bf16x8*)(Bb + brow + (n + 2) * 2048 + q1);
    }
    WAITLGKM0();
    SCHED0();
    __builtin_amdgcn_s_setprio(1);
#pragma unroll
    for (int m = 0; m < 4; ++m)
#pragma unroll
      for (int n = 0; n < 2; ++n) {
        acc[m][n + 2] = __builtin_amdgcn_mfma_f32_16x16x32_bf16(aq0[m], bB0[n], acc[m][n + 2], 0, 0, 0);
        acc[m][n + 2] = __builtin_amdgcn_mfma_f32_16x16x32_bf16(aq1[m], bB1[n], acc[m][n + 2], 0, 0, 0);
      }
    __builtin_amdgcn_s_setprio(0);
    SCHED0();

    // ---- P3: A m4-7 (8, reuse regs); q10 ----
#pragma unroll
    for (int m = 0; m < 4; ++m) {
      aq0[m] = *(const bf16x8*)(Ab + arow + (m + 4) * 2048 + q0);
      aq1[m] = *(const bf16x8*)(Ab + arow + (m + 4) * 2048 + q1);
    }
    WAITLGKM0();
    SCHED0();
    __builtin_amdgcn_s_setprio(1);
#pragma unroll
    for (int m = 0; m < 4; ++m)
#pragma unroll
      for (int n = 0; n < 2; ++n) {
        acc[m + 4][n] = __builtin_amdgcn_mfma_f32_16x16x32_bf16(aq0[m], bA0[n], acc[m + 4][n], 0, 0, 0);
        acc[m + 4][n] = __builtin_amdgcn_mfma_f32_16x16x32_bf16(aq1[m], bA1[n], acc[m + 4][n], 0, 0, 0);
      }
    __builtin_amdgcn_s_setprio(0);
    SCHED0();

    // ---- P4: q11; drain stages; single barrier ----
    __builtin_amdgcn_s_setprio(1);
#pragma unroll
    for (int m = 0; m < 4; ++m)
#pragma unroll
      for (int n = 0; n < 2; ++n) {
        acc[m + 4][n + 2] = __builtin_amdgcn_mfma_f32_16x16x32_bf16(aq0[m], bB0[n], acc[m + 4][n + 2], 0, 0, 0);
        acc[m + 4][n + 2] = __builtin_amdgcn_mfma_f32_16x16x32_bf16(aq1[m], bB1[n], acc[m + 4][n + 2], 0, 0, 0);
      }
    __builtin_amdgcn_s_setprio(0);
    WAITVM0();     // stages issued ~3.5 phases ago -> effectively free
    BARRIER();     // the only block-wide sync per tile
  }
#undef STAGEH

  // ---- epilogue: C/D layout col = lane&15, row = (lane>>4)*4 + q ----
  const int c4 = cq * 4;
#pragma unroll
  for (int n = 0; n < 4; ++n) {
    const int col = bn0 + wn + n * 16 + fr;
    const float bv = bias[col];
#pragma unroll
    for (int m = 0; m < 8; ++m) {
      const size_t rowb = (size_t)(bm0 + wm + m * 16 + c4);
#pragma unroll
      for (int q = 0; q < 4; ++q)
        C[(rowb + q) * (size_t)Mn + col] = acc[m][n][q] + bv;
    }
  }
}

extern "C" void kernel_launch(void* const* d_in, const int* in_sizes, int n_in,
                              void* d_out, int out_size, void* d_ws, size_t ws_size,
                              hipStream_t stream) {
  const float* x     = (const float*)d_in[0];
  const float* dw    = (const float*)d_in[1];
  const float* bias  = (const float*)d_in[2];
  const float* sv    = (const float*)d_in[3];
  const int*   rows  = (const int*)d_in[4];
  const int*   cols  = (const int*)d_in[5];
  float* out = (float*)d_out;

  const int  Mn = in_sizes[2];                       // 4096
  const long wElems = (long)in_sizes[1];             // M*K
  const int  K  = (int)(wElems / Mn);                // 4096
  const long xElems = (long)in_sizes[0];             // T*K
  const int  Tm = (int)(xElems / K);                 // 8192
  const int  nnz = in_sizes[3];

  unsigned short* Wb = (unsigned short*)d_ws;        // [M*K] bf16
  unsigned short* Xb = Wb + wElems;                  // [T*K] bf16

  cvt_f32_bf16<<<2048, 256, 0, stream>>>(dw, Wb, wElems / 8);
  sparse_scatter<<<(nnz + 255) / 256, 256, 0, stream>>>(dw, sv, rows, cols, Wb, nnz, K);
  cvt_f32_bf16<<<2048, 256, 0, stream>>>(x, Xb, xElems / 8);

  dim3 grid((Tm >> 8) * (Mn >> 8));                  // 32*16 = 512
  gemm256f<<<grid, 512, 131072, stream>>>(Xb, Wb, bias, out, Tm, Mn, K);
}